// Round 9
// baseline (234.392 us; speedup 1.0000x reference)
//
#include <hip/hip_runtime.h>

#define S 2048
#define D 768
#define NH 12
#define HD 64
#define TD (3 * D)

typedef __bf16 bf16_t;
typedef __bf16 v8bf __attribute__((ext_vector_type(8)));
typedef __bf16 v4bf __attribute__((ext_vector_type(4)));
typedef float v4f __attribute__((ext_vector_type(4)));

// ---------- reductions ----------
__device__ __forceinline__ float wave_reduce_sum(float v) {
#pragma unroll
    for (int o = 32; o > 0; o >>= 1) v += __shfl_down(v, o, 64);
    return v;
}
__device__ float block_reduce_sum(float v) {
    __shared__ float t4[4];
    int lane = threadIdx.x & 63, wid = threadIdx.x >> 6;
    v = wave_reduce_sum(v);
    __syncthreads();
    if (lane == 0) t4[wid] = v;
    __syncthreads();
    return t4[0] + t4[1] + t4[2] + t4[3];
}

// ---------- fused: blocks [0,S) do add+LN; blocks [S,...) convert weights ----------
#define NW0 (TD * D / 4)
#define NW1 (D * D / 4)
#define NW2 ((D / 2) * D / 4)
#define NW3 (D * (D / 2) / 4)
#define NWALL (NW0 + NW1 + NW2 + NW3)

__global__ __launch_bounds__(256) void addln_cvt(const float* __restrict__ A, const float* __restrict__ Bv,
                                                 const float* __restrict__ g, const float* __restrict__ be,
                                                 bf16_t* __restrict__ out,
                                                 const float* __restrict__ s0, const float* __restrict__ s1,
                                                 const float* __restrict__ s2, const float* __restrict__ s3,
                                                 bf16_t* __restrict__ d0, bf16_t* __restrict__ d1,
                                                 bf16_t* __restrict__ d2, bf16_t* __restrict__ d3) {
    int blk = blockIdx.x, t = threadIdx.x;
    if (blk >= S) {
        int i = (blk - S) * 256 + t;
        const float* sp; bf16_t* dp;
        if (i < NW0) { sp = s0; dp = d0; }
        else if (i < NW0 + NW1) { sp = s1; dp = d1; i -= NW0; }
        else if (i < NW0 + NW1 + NW2) { sp = s2; dp = d2; i -= NW0 + NW1; }
        else if (i < NWALL) { sp = s3; dp = d3; i -= NW0 + NW1 + NW2; }
        else return;
        float4 v = ((const float4*)sp)[i];
        v4bf o = {(bf16_t)v.x, (bf16_t)v.y, (bf16_t)v.z, (bf16_t)v.w};
        *(v4bf*)(dp + (size_t)i * 4) = o;
        return;
    }
    int row = blk;
    const float* a = A + (size_t)row * D;
    const float* b = Bv + (size_t)row * D;
    float x[3];
    float s = 0.f;
#pragma unroll
    for (int i = 0; i < 3; ++i) { int c = t + 256 * i; x[i] = a[c] + b[c]; s += x[i]; }
    float mean = block_reduce_sum(s) * (1.0f / D);
    float vs = 0.f;
#pragma unroll
    for (int i = 0; i < 3; ++i) { float d = x[i] - mean; vs += d * d; }
    float var = block_reduce_sum(vs) * (1.0f / D);
    float rstd = rsqrtf(var + 1e-5f);
#pragma unroll
    for (int i = 0; i < 3; ++i) {
        int c = t + 256 * i;
        out[(size_t)row * D + c] = (bf16_t)((x[i] - mean) * rstd * g[c] + be[c]);
    }
}

// ---------- MFMA GEMM (QKV only): C[M,N] = A[M,K] @ B[N,K]^T + bias[N] ----------
#define GBK 64

template <int TM, int TN>
__global__ __launch_bounds__(256) void gemm_mfma(const bf16_t* __restrict__ A, const bf16_t* __restrict__ B,
                                                 const float* __restrict__ bias, bf16_t* __restrict__ C,
                                                 int M, int N, int K) {
    constexpr int CA = TM * 8;
    constexpr int CHUNKS = (TM + TN) * 8;
    constexpr int P = CHUNKS / 256;
    static_assert(CHUNKS % 256 == 0, "chunk passes must be exact");
    constexpr int MI = TM / 32, NI = TN / 32;
    __shared__ bf16_t As[TM * GBK];
    __shared__ bf16_t Bs[TN * GBK];
    const int t = threadIdx.x;
    const int lane = t & 63, wave = t >> 6;
    const int wr = (wave >> 1) * (TM / 2), wc = (wave & 1) * (TN / 2);
    const int m0 = blockIdx.y * TM, n0 = blockIdx.x * TN;
    const int lm = lane & 15, q = lane >> 4;

    const bf16_t* gsrc[P];
    bf16_t* ldst[P];
#pragma unroll
    for (int p = 0; p < P; ++p) {
        int c = t + 256 * p;
        if (c < CA) {
            int slab = c / (TM * 4), r4 = c % (TM * 4);
            int row = r4 >> 2, c4 = r4 & 3;
            gsrc[p] = A + (size_t)(m0 + row) * K + slab * 32 + c4 * 8;
            ldst[p] = As + slab * (TM * 32) + row * 32 + c4 * 8;
        } else {
            int cc = c - CA;
            int slab = cc / (TN * 4), r4 = cc % (TN * 4);
            int row = r4 >> 2, c4 = r4 & 3;
            gsrc[p] = B + (size_t)(n0 + row) * K + slab * 32 + c4 * 8;
            ldst[p] = Bs + slab * (TN * 32) + row * 32 + c4 * 8;
        }
    }

    v4f acc[MI][NI] = {};

    for (int k0 = 0; k0 < K; k0 += GBK) {
#pragma unroll
        for (int p = 0; p < P; ++p)
            __builtin_amdgcn_global_load_lds((const __attribute__((address_space(1))) void*)(gsrc[p] + k0),
                                             (__attribute__((address_space(3))) void*)ldst[p], 16, 0, 0);
        __syncthreads();

        v8bf af[2][MI], bfr[2][NI];
#pragma unroll
        for (int s = 0; s < 2; ++s) {
#pragma unroll
            for (int i = 0; i < MI; ++i)
                af[s][i] = *(const v8bf*)(As + s * (TM * 32) + (wr + i * 16 + lm) * 32 + q * 8);
#pragma unroll
            for (int j = 0; j < NI; ++j)
                bfr[s][j] = *(const v8bf*)(Bs + s * (TN * 32) + (wc + j * 16 + lm) * 32 + q * 8);
        }
#pragma unroll
        for (int s = 0; s < 2; ++s)
#pragma unroll
            for (int i = 0; i < MI; ++i)
#pragma unroll
                for (int j = 0; j < NI; ++j)
                    acc[i][j] = __builtin_amdgcn_mfma_f32_16x16x32_bf16(af[s][i], bfr[s][j], acc[i][j], 0, 0, 0);
        __syncthreads();
    }

#pragma unroll
    for (int i = 0; i < MI; ++i)
#pragma unroll
        for (int j = 0; j < NI; ++j) {
            int col = n0 + wc + j * 16 + lm;
            float bs = bias[col];
#pragma unroll
            for (int r = 0; r < 4; ++r) {
                int row = m0 + wr + i * 16 + q * 4 + r;
                C[(size_t)row * N + col] = (bf16_t)(acc[i][j][r] + bs);
            }
        }
}

// ---------- sparse masked attention (block per row; ILP'd PV) ----------
__global__ __launch_bounds__(256) void attn_sparse(const bf16_t* __restrict__ qkv, const int* __restrict__ adj,
                                                   bf16_t* __restrict__ O) {
    __shared__ int s_idx[128];
    __shared__ int s_cnt;
    __shared__ float s_q[D];
    __shared__ float s_p[NH][128];

    const int row = blockIdx.x, t = threadIdx.x;
    const int lane = t & 63, wave = t >> 6;
    if (t == 0) s_cnt = 0;
    __syncthreads();

    const int4* arow = (const int4*)(adj + (size_t)row * S);
#pragma unroll
    for (int p = 0; p < 2; ++p) {
        int4 v = arow[t + 256 * p];
        int base = (t + 256 * p) * 4;
        if (v.x) { int k = atomicAdd(&s_cnt, 1); if (k < 128) s_idx[k] = base + 0; }
        if (v.y) { int k = atomicAdd(&s_cnt, 1); if (k < 128) s_idx[k] = base + 1; }
        if (v.z) { int k = atomicAdd(&s_cnt, 1); if (k < 128) s_idx[k] = base + 2; }
        if (v.w) { int k = atomicAdd(&s_cnt, 1); if (k < 128) s_idx[k] = base + 3; }
    }
    for (int c = t; c < D; c += 256) s_q[c] = (float)qkv[(size_t)row * TD + c];
    __syncthreads();
    const int n = (s_cnt < 128) ? s_cnt : 128;

    for (int it = t; it < n * NH; it += 256) {
        int h = it / n, i = it - h * n;
        int j = s_idx[i];
        const v8bf* kp = (const v8bf*)(qkv + (size_t)j * TD + D + h * HD);
        const float4* qp = (const float4*)(s_q + h * HD);
        float dot = 0.f;
#pragma unroll
        for (int c = 0; c < 8; ++c) {
            v8bf kv = kp[c];
            float4 qa = qp[2 * c], qb = qp[2 * c + 1];
            dot += qa.x * (float)kv[0] + qa.y * (float)kv[1] + qa.z * (float)kv[2] + qa.w * (float)kv[3]
                 + qb.x * (float)kv[4] + qb.y * (float)kv[5] + qb.z * (float)kv[6] + qb.w * (float)kv[7];
        }
        s_p[h][i] = dot * 0.125f;
    }
    __syncthreads();

    for (int h = wave; h < NH; h += 4) {
        float v0 = (lane < n) ? s_p[h][lane] : -1e30f;
        float v1 = (lane + 64 < n) ? s_p[h][lane + 64] : -1e30f;
        float m = fmaxf(v0, v1);
#pragma unroll
        for (int o = 32; o > 0; o >>= 1) m = fmaxf(m, __shfl_xor(m, o, 64));
        float p0 = (lane < n) ? __expf(v0 - m) : 0.f;
        float p1 = (lane + 64 < n) ? __expf(v1 - m) : 0.f;
        float sm = p0 + p1;
#pragma unroll
        for (int o = 32; o > 0; o >>= 1) sm += __shfl_xor(sm, o, 64);
        float inv = 1.f / sm;
        if (lane < n) s_p[h][lane] = p0 * inv;
        if (lane + 64 < n) s_p[h][lane + 64] = p1 * inv;
    }
    __syncthreads();

    for (int o = t; o < D; o += 256) {
        int h = o >> 6, e = o & 63;
        const float* pp = s_p[h];
        const bf16_t* vbase = qkv + 2 * D + h * HD + e;
        float a0 = 0.f, a1 = 0.f, a2 = 0.f, a3 = 0.f;
        int i = 0;
        for (; i + 4 <= n; i += 4) {
            int j0 = s_idx[i], j1 = s_idx[i + 1], j2 = s_idx[i + 2], j3 = s_idx[i + 3];
            a0 += pp[i]     * (float)vbase[(size_t)j0 * TD];
            a1 += pp[i + 1] * (float)vbase[(size_t)j1 * TD];
            a2 += pp[i + 2] * (float)vbase[(size_t)j2 * TD];
            a3 += pp[i + 3] * (float)vbase[(size_t)j3 * TD];
        }
        for (; i < n; ++i) a0 += pp[i] * (float)vbase[(size_t)s_idx[i] * TD];
        O[(size_t)row * D + o] = (bf16_t)((a0 + a1) + (a2 + a3));
    }
}

// ---------- fully fused tail: out-proj + resid + LN1 + FF1 + FF2 + resid + LN2 ----------
// One block per 8-row band (256 blocks). All intermediates live in LDS; weights
// streamed L2 -> registers (B-fragment layout loaded directly: n=lane&15 rows,
// k=quad*8 offsets — byte-identical to what the LDS path would deliver).
#define RB 8

__global__ __launch_bounds__(256) void tail_fused(
    const bf16_t* __restrict__ attn_o, const bf16_t* __restrict__ x_in,
    const bf16_t* __restrict__ wo, const float* __restrict__ bo,
    const float* __restrict__ g1, const float* __restrict__ be1,
    const bf16_t* __restrict__ w1, const float* __restrict__ b1,
    const bf16_t* __restrict__ w2, const float* __restrict__ b2,
    const float* __restrict__ g2, const float* __restrict__ be2,
    float* __restrict__ out) {
    __shared__ bf16_t Afrag[24 * 16 * 32];   // 24 KB: A-frags (attn rows, later x1)
    __shared__ bf16_t Scr[RB * D];           // 12 KB: x_in resid, later ffh frags (12*16*32)
    __shared__ bf16_t Ybuf[RB * D];          // 12 KB: y1 staging, later y2
    const int t = threadIdx.x, lane = t & 63, wave = t >> 6;
    const int lm = lane & 15, q = lane >> 4;
    const int m0 = blockIdx.x * RB;

    // stage attn_o rows into A-frag layout [k-slab][row16][k32]; x_in rows flat
    {
        int row = t >> 5, cc = t & 31;
#pragma unroll
        for (int i = 0; i < 3; ++i) {
            int c0 = (cc + 32 * i) * 8;
            *(v8bf*)(Afrag + (c0 >> 5) * 512 + row * 32 + (c0 & 31)) =
                *(const v8bf*)(attn_o + (size_t)(m0 + row) * D + c0);
            *(v8bf*)(Scr + row * D + c0) =
                *(const v8bf*)(x_in + (size_t)(m0 + row) * D + c0);
        }
    }
    __syncthreads();

    // ---- stage A: y1 = attn @ wo^T + bo + x_in (48 col-tiles; 12/wave, 3-chain ILP) ----
#pragma unroll 1
    for (int g = 0; g < 4; ++g) {
        const int ct0 = wave * 12 + g * 3;
        v4f a0 = {}, a1 = {}, a2 = {};
        const bf16_t* b0p = wo + (size_t)(ct0 * 16 + lm) * D + q * 8;
        const bf16_t* b1p = b0p + (size_t)16 * D;
        const bf16_t* b2p = b0p + (size_t)32 * D;
        const bf16_t* ap = Afrag + lm * 32 + q * 8;
#pragma unroll 4
        for (int k = 0; k < 24; ++k) {
            v8bf a = *(const v8bf*)(ap + k * 512);
            a0 = __builtin_amdgcn_mfma_f32_16x16x32_bf16(a, *(const v8bf*)(b0p + k * 32), a0, 0, 0, 0);
            a1 = __builtin_amdgcn_mfma_f32_16x16x32_bf16(a, *(const v8bf*)(b1p + k * 32), a1, 0, 0, 0);
            a2 = __builtin_amdgcn_mfma_f32_16x16x32_bf16(a, *(const v8bf*)(b2p + k * 32), a2, 0, 0, 0);
        }
        if (q < 2) {
            v4f ac[3] = {a0, a1, a2};
#pragma unroll
            for (int j = 0; j < 3; ++j) {
                int col = (ct0 + j) * 16 + lm;
                float bb = bo[col];
#pragma unroll
                for (int r = 0; r < 4; ++r) {
                    int row = q * 4 + r;
                    Ybuf[row * D + col] = (bf16_t)(ac[j][r] + bb + (float)Scr[row * D + col]);
                }
            }
        }
    }
    __syncthreads();

    // ---- LN1: wave handles rows {2w, 2w+1}; x1 -> Afrag (frag layout) ----
#pragma unroll 1
    for (int rr = 0; rr < 2; ++rr) {
        const int row = wave * 2 + rr;
        float v[12];
        float s = 0.f, s2 = 0.f;
#pragma unroll
        for (int e = 0; e < 12; ++e) {
            v[e] = (float)Ybuf[row * D + lane + 64 * e];
            s += v[e]; s2 += v[e] * v[e];
        }
#pragma unroll
        for (int o = 32; o > 0; o >>= 1) { s += __shfl_xor(s, o, 64); s2 += __shfl_xor(s2, o, 64); }
        float mean = s * (1.0f / D);
        float rstd = rsqrtf(s2 * (1.0f / D) - mean * mean + 1e-5f);
#pragma unroll
        for (int e = 0; e < 12; ++e) {
            int c = lane + 64 * e;
            Afrag[(c >> 5) * 512 + row * 32 + (c & 31)] = (bf16_t)((v[e] - mean) * rstd * g1[c] + be1[c]);
        }
    }
    __syncthreads();

    // ---- stage B: ffh = relu(x1 @ w1^T + b1) (24 col-tiles; 6/wave) -> Scr frags ----
#pragma unroll 1
    for (int g = 0; g < 2; ++g) {
        const int ct0 = wave * 6 + g * 3;
        v4f a0 = {}, a1 = {}, a2 = {};
        const bf16_t* b0p = w1 + (size_t)(ct0 * 16 + lm) * D + q * 8;
        const bf16_t* b1p = b0p + (size_t)16 * D;
        const bf16_t* b2p = b0p + (size_t)32 * D;
        const bf16_t* ap = Afrag + lm * 32 + q * 8;
#pragma unroll 4
        for (int k = 0; k < 24; ++k) {
            v8bf a = *(const v8bf*)(ap + k * 512);
            a0 = __builtin_amdgcn_mfma_f32_16x16x32_bf16(a, *(const v8bf*)(b0p + k * 32), a0, 0, 0, 0);
            a1 = __builtin_amdgcn_mfma_f32_16x16x32_bf16(a, *(const v8bf*)(b1p + k * 32), a1, 0, 0, 0);
            a2 = __builtin_amdgcn_mfma_f32_16x16x32_bf16(a, *(const v8bf*)(b2p + k * 32), a2, 0, 0, 0);
        }
        if (q < 2) {
            v4f ac[3] = {a0, a1, a2};
#pragma unroll
            for (int j = 0; j < 3; ++j) {
                int col = (ct0 + j) * 16 + lm;
                float bb = b1[col];
#pragma unroll
                for (int r = 0; r < 4; ++r) {
                    int row = q * 4 + r;
                    Scr[(col >> 5) * 512 + row * 32 + (col & 31)] = (bf16_t)fmaxf(ac[j][r] + bb, 0.f);
                }
            }
        }
    }
    __syncthreads();

    // ---- stage C: y2 = ffh @ w2^T + b2 + x1 (K=384; 48 col-tiles; 12/wave) -> Ybuf ----
#pragma unroll 1
    for (int g = 0; g < 4; ++g) {
        const int ct0 = wave * 12 + g * 3;
        v4f a0 = {}, a1 = {}, a2 = {};
        const bf16_t* b0p = w2 + (size_t)(ct0 * 16 + lm) * 384 + q * 8;
        const bf16_t* b1p = b0p + (size_t)16 * 384;
        const bf16_t* b2p = b0p + (size_t)32 * 384;
        const bf16_t* ap = Scr + lm * 32 + q * 8;
#pragma unroll
        for (int k = 0; k < 12; ++k) {
            v8bf a = *(const v8bf*)(ap + k * 512);
            a0 = __builtin_amdgcn_mfma_f32_16x16x32_bf16(a, *(const v8bf*)(b0p + k * 32), a0, 0, 0, 0);
            a1 = __builtin_amdgcn_mfma_f32_16x16x32_bf16(a, *(const v8bf*)(b1p + k * 32), a1, 0, 0, 0);
            a2 = __builtin_amdgcn_mfma_f32_16x16x32_bf16(a, *(const v8bf*)(b2p + k * 32), a2, 0, 0, 0);
        }
        if (q < 2) {
            v4f ac[3] = {a0, a1, a2};
#pragma unroll
            for (int j = 0; j < 3; ++j) {
                int col = (ct0 + j) * 16 + lm;
                float bb = b2[col];
#pragma unroll
                for (int r = 0; r < 4; ++r) {
                    int row = q * 4 + r;
                    float x1v = (float)Afrag[(col >> 5) * 512 + row * 32 + (col & 31)];
                    Ybuf[row * D + col] = (bf16_t)(ac[j][r] + bb + x1v);
                }
            }
        }
    }
    __syncthreads();

    // ---- LN2 -> fp32 out ----
#pragma unroll 1
    for (int rr = 0; rr < 2; ++rr) {
        const int row = wave * 2 + rr;
        float v[12];
        float s = 0.f, s2 = 0.f;
#pragma unroll
        for (int e = 0; e < 12; ++e) {
            v[e] = (float)Ybuf[row * D + lane + 64 * e];
            s += v[e]; s2 += v[e] * v[e];
        }
#pragma unroll
        for (int o = 32; o > 0; o >>= 1) { s += __shfl_xor(s, o, 64); s2 += __shfl_xor(s2, o, 64); }
        float mean = s * (1.0f / D);
        float rstd = rsqrtf(s2 * (1.0f / D) - mean * mean + 1e-5f);
#pragma unroll
        for (int e = 0; e < 12; ++e) {
            int c = lane + 64 * e;
            out[(size_t)(m0 + row) * D + c] = (v[e] - mean) * rstd * g2[c] + be2[c];
        }
    }
}

// ---------- launch ----------
extern "C" void kernel_launch(void* const* d_in, const int* in_sizes, int n_in,
                              void* d_out, int out_size, void* d_ws, size_t ws_size,
                              hipStream_t stream) {
    const float* exp_e = (const float*)d_in[0];
    const float* pert  = (const float*)d_in[1];
    const float* w_in  = (const float*)d_in[2];
    const float* b_in  = (const float*)d_in[3];
    const float* w_out = (const float*)d_in[4];
    const float* b_out = (const float*)d_in[5];
    const float* g0  = (const float*)d_in[6];
    const float* be0 = (const float*)d_in[7];
    const float* g1  = (const float*)d_in[8];
    const float* be1 = (const float*)d_in[9];
    const float* g2  = (const float*)d_in[10];
    const float* be2 = (const float*)d_in[11];
    const float* w1  = (const float*)d_in[12];
    const float* b1  = (const float*)d_in[13];
    const float* w2  = (const float*)d_in[14];
    const float* b2  = (const float*)d_in[15];
    const int*   adj = (const int*)d_in[16];
    float* out = (float*)d_out;

    const size_t SD = (size_t)S * D;
    bf16_t* wb_in  = (bf16_t*)d_ws;               // [2304*768]
    bf16_t* wb_out = wb_in + (size_t)TD * D;      // [768*768]
    bf16_t* wb_1   = wb_out + (size_t)D * D;      // [384*768]
    bf16_t* wb_2   = wb_1 + (size_t)(D / 2) * D;  // [768*384]
    bf16_t* x_in   = wb_2 + (size_t)D * (D / 2);  // [S*D]
    bf16_t* qkv    = x_in + SD;                   // [S*3D]
    bf16_t* attn_o = qkv + 3 * SD;                // [S*D]

    const int CVTB = (NWALL + 255) / 256;
    addln_cvt<<<S + CVTB, 256, 0, stream>>>(exp_e, pert, g0, be0, x_in,
                                            w_in, w_out, w1, w2, wb_in, wb_out, wb_1, wb_2);
    gemm_mfma<64, 128><<<dim3(TD / 128, S / 64), 256, 0, stream>>>(x_in, wb_in, b_in, qkv, S, TD, D);
    attn_sparse<<<S, 256, 0, stream>>>(qkv, adj, attn_o);
    tail_fused<<<S / RB, 256, 0, stream>>>(attn_o, x_in, wb_out, b_out, g1, be1,
                                           wb_1, b1, wb_2, b2, g2, be2, out);
}